// Round 2
// baseline (381.762 us; speedup 1.0000x reference)
//
#include <hip/hip_runtime.h>
#include <hip/hip_bf16.h>
#include <stdint.h>

typedef __attribute__((ext_vector_type(8))) short short8;   // 8 bf16 in 4 VGPRs
typedef __attribute__((ext_vector_type(4))) float floatx4;
typedef unsigned long long ull;

__device__ __forceinline__ floatx4 mfma_bf16(short8 a, short8 b, floatx4 c) {
  return __builtin_amdgcn_mfma_f32_16x16x32_bf16(a, b, c, 0, 0, 0);
}

// async global->LDS, 16B per lane; lds must be the wave-uniform base (lane lands at +lane*16)
__device__ __forceinline__ void async16(const void* g, void* lds) {
  __builtin_amdgcn_global_load_lds(
      (const __attribute__((address_space(1))) unsigned int*)g,
      (__attribute__((address_space(3))) unsigned int*)lds, 16, 0, 0);
}

// convert 8 contiguous fp32 -> 8 bf16 (one 16B store)
__device__ __forceinline__ void cvt8_store(const float* __restrict__ src,
                                           __hip_bfloat16* __restrict__ dst) {
  float4 a = *(const float4*)src;
  float4 b = *(const float4*)(src + 4);
  __hip_bfloat16 t[8];
  t[0] = __float2bfloat16(a.x); t[1] = __float2bfloat16(a.y);
  t[2] = __float2bfloat16(a.z); t[3] = __float2bfloat16(a.w);
  t[4] = __float2bfloat16(b.x); t[5] = __float2bfloat16(b.y);
  t[6] = __float2bfloat16(b.z); t[7] = __float2bfloat16(b.w);
  *(uint4*)dst = *(const uint4*)t;
}

__device__ __forceinline__ float sigm_f(float x) { return 1.f / (1.f + __expf(-x)); }
// tanh = 1 - 2/(1+e^{2x}); saturates correctly: x->+inf => 1, x->-inf => -1. ~1e-6 err.
__device__ __forceinline__ float tanh_f(float x) {
  return 1.f - 2.f / (1.f + __expf(2.f * x));
}

// ---------------- prep: r<2048 Xs gather | <4096 WhhB | <6144 WihB | else fcWB
__global__ __launch_bounds__(256) void prep(
    const float* __restrict__ feat, const int* __restrict__ caps,
    const float* __restrict__ emb,  const float* __restrict__ Whh,
    const float* __restrict__ Wih,  const float* __restrict__ fcW,
    __hip_bfloat16* __restrict__ Xs,   __hip_bfloat16* __restrict__ WhhB,
    __hip_bfloat16* __restrict__ WihB, __hip_bfloat16* __restrict__ fcWB) {
  int tid = blockIdx.x * 256 + threadIdx.x;
  int r = tid >> 6;
  int ch = (tid & 63) * 8;
  const float* src;
  __hip_bfloat16* dst;
  if (r < 2048) {
    int t = r >> 6, b = r & 63;
    bool i64 = (caps[1] == 0) & (caps[3] == 0) & (caps[5] == 0) & (caps[7] == 0) &
               (caps[9] == 0) & (caps[11] == 0) & (caps[13] == 0);
    if (t == 0) {
      src = feat + (size_t)b * 512 + ch;
    } else {
      int idx = i64 ? caps[(size_t)(b * 32 + t) * 2] : caps[b * 32 + t];
      idx = idx < 0 ? 0 : (idx > 9999 ? 9999 : idx);
      src = emb + (size_t)idx * 512 + ch;
    }
    dst = Xs + (size_t)r * 512 + ch;
  } else if (r < 4096) {
    src = Whh + (size_t)(r - 2048) * 512 + ch;  dst = WhhB + (size_t)(r - 2048) * 512 + ch;
  } else if (r < 6144) {
    src = Wih + (size_t)(r - 4096) * 512 + ch;  dst = WihB + (size_t)(r - 4096) * 512 + ch;
  } else {
    src = fcW + (size_t)(r - 6144) * 512 + ch;  dst = fcWB + (size_t)(r - 6144) * 512 + ch;
  }
  cvt8_store(src, dst);
}

// ---------------- NT GEMM: C[M x N] = A[M x 512](bf16) * B[N x 512]^T + bias
// bf16B: B already bf16 -> async global_load_lds staging; else fp32->bf16 cvt staging.
// mode 0: outF[row*ldc+col] = acc + b1[col] + b2[col]
// mode 1: outF[((row&63)*32+(row>>6))*ldc+col] = acc + b1[col]   (row = t*64+b -> [B,T,V])
__global__ __launch_bounds__(256) void gemm_nt(
    const __hip_bfloat16* __restrict__ A,
    const void* __restrict__ Bv,
    const float* __restrict__ b1,
    const float* __restrict__ b2,
    float* __restrict__ outF,
    int Nrows, int ldc, int mode, int bf16B) {
  const int K = 512;
  __shared__ __align__(16) __hip_bfloat16 As[128 * 32];
  __shared__ __align__(16) __hip_bfloat16 Bs[128 * 32];
  const int tid = threadIdx.x;
  const int ib = blockIdx.x, jb = blockIdx.y;
  const int w = tid >> 6, l = tid & 63, lr = l & 15, lq = l >> 4;
  const int wr = (w & 1) * 64, wc = (w >> 1) * 64;
  floatx4 acc[4][4] = {};
  for (int kt = 0; kt < 16; ++kt) {
    const int k0 = kt * 32;
#pragma unroll
    for (int it = 0; it < 2; ++it) {
      const int flat0 = it * 256 + w * 64;   // wave-uniform LDS base index
      const int flat = flat0 + l;
      const int row = flat >> 2, c8 = (flat & 3) * 8;
      async16(A + (size_t)(ib * 128 + row) * K + k0 + c8, As + flat0 * 8);
      int rb = jb * 128 + row;
      if (rb > Nrows - 1) rb = Nrows - 1;    // clamp tail (dup reads; cols guarded on store)
      if (bf16B) {
        async16((const __hip_bfloat16*)Bv + (size_t)rb * K + k0 + c8, Bs + flat0 * 8);
      } else {
        cvt8_store((const float*)Bv + (size_t)rb * K + k0 + c8, Bs + flat * 8);
      }
    }
    __syncthreads();
    short8 af[4], bfr[4];
#pragma unroll
    for (int mt = 0; mt < 4; ++mt)
      af[mt] = *(const short8*)(As + (wr + mt * 16 + lr) * 32 + lq * 8);
#pragma unroll
    for (int nt = 0; nt < 4; ++nt)
      bfr[nt] = *(const short8*)(Bs + (wc + nt * 16 + lr) * 32 + lq * 8);
#pragma unroll
    for (int mt = 0; mt < 4; ++mt)
#pragma unroll
      for (int nt = 0; nt < 4; ++nt)
        acc[mt][nt] = mfma_bf16(af[mt], bfr[nt], acc[mt][nt]);
    __syncthreads();
  }
#pragma unroll
  for (int mt = 0; mt < 4; ++mt) {
#pragma unroll
    for (int nt = 0; nt < 4; ++nt) {
      int col = jb * 128 + wc + nt * 16 + lr;
      if (col < Nrows) {
        float bias = b1[col] + (b2 ? b2[col] : 0.f);
#pragma unroll
        for (int r = 0; r < 4; ++r) {
          int row = ib * 128 + wr + mt * 16 + lq * 4 + r;
          size_t orow = mode ? (size_t)((row & 63) * 32 + (row >> 6)) : (size_t)row;
          outF[orow * ldc + col] = acc[mt][nt][r] + bias;
        }
      }
    }
  }
}

// ---------------- LSTM: 64 blocks (4 bg x 16 ug). Chain-latency optimized:
//  * all 32 h-chunk LLC loads hoisted into hu[32] BEFORE the MFMA loop -> one
//    pipelined LLC round-trip per step instead of several serialized ones
//  * per-ug parallel release flags (one store/word) instead of a 16-way
//    serialized fetch_add RMW on a single word; consumer polls 8 ull loads
//  * fast tanh (exp-form, branch-free) on the critical path
__global__ __launch_bounds__(256, 1) void lstm_seq(
    const float* __restrict__ xp,            // [32][64][2048] fp32 (biases included)
    const __hip_bfloat16* __restrict__ Whh,  // [2048][512] bf16
    __hip_bfloat16* __restrict__ hseq,       // [32][64][512] bf16
    unsigned* __restrict__ cnt) {            // [32][4] flag rows, 128 B apart (16 words used)
  const int bg = blockIdx.x >> 4;   // 0..3  (16 batch rows)
  const int ug = blockIdx.x & 15;   // 0..15 (32 hidden units)
  const int tid = threadIdx.x;
  const int w = tid >> 6, l = tid & 63, lr = l & 15, lq = l >> 4;
  const int bl = tid >> 5, uu = tid & 31;
  __shared__ float gbuf[4][16][32];
  __shared__ __align__(8) __hip_bfloat16 hbuf[16][32];
  float c0 = 0.f, c1 = 0.f;

  // B fragments are constant across t: preload all 32 (128 regs)
  short8 B0[16], B1[16];
  {
    const __hip_bfloat16* w0 = Whh + (size_t)(w * 512 + ug * 32 + lr) * 512 + lq * 8;
    const __hip_bfloat16* w1 = w0 + (size_t)16 * 512;
#pragma unroll
    for (int kk = 0; kk < 16; ++kk) {
      B0[kk] = *(const short8*)(w0 + kk * 32);
      B1[kk] = *(const short8*)(w1 + kk * 32);
    }
  }

  for (int t = 0; t < 32; ++t) {
    // prefetch this step's xp (independent of h) — in flight during the spin
    const float* xr0 = xp + ((size_t)t * 64 + bg * 16 + bl) * 2048 + ug * 32 + uu;
    const float* xr1 = xr0 + (size_t)8 * 2048;
    float xi0 = xr0[0], xf0 = xr0[512], xg0 = xr0[1024], xo0 = xr0[1536];
    float xi1 = xr1[0], xf1 = xr1[512], xg1 = xr1[1024], xo1 = xr1[1536];

    floatx4 a0 = {}, a1 = {};
    if (t > 0) {
      if (tid == 0) {
        // all 16 producer words of (t-1,bg) must be 1: AND of the 8 ulls
        // equals 0x0000000100000001 iff every word is exactly 1.
        const ull* f = (const ull*)(cnt + ((t - 1) * 4 + bg) * 32);
        for (;;) {
          ull v = __hip_atomic_load(f + 0, __ATOMIC_RELAXED, __HIP_MEMORY_SCOPE_AGENT);
          v &= __hip_atomic_load(f + 1, __ATOMIC_RELAXED, __HIP_MEMORY_SCOPE_AGENT);
          v &= __hip_atomic_load(f + 2, __ATOMIC_RELAXED, __HIP_MEMORY_SCOPE_AGENT);
          v &= __hip_atomic_load(f + 3, __ATOMIC_RELAXED, __HIP_MEMORY_SCOPE_AGENT);
          v &= __hip_atomic_load(f + 4, __ATOMIC_RELAXED, __HIP_MEMORY_SCOPE_AGENT);
          v &= __hip_atomic_load(f + 5, __ATOMIC_RELAXED, __HIP_MEMORY_SCOPE_AGENT);
          v &= __hip_atomic_load(f + 6, __ATOMIC_RELAXED, __HIP_MEMORY_SCOPE_AGENT);
          v &= __hip_atomic_load(f + 7, __ATOMIC_RELAXED, __HIP_MEMORY_SCOPE_AGENT);
          if (v == 0x0000000100000001ULL) break;
          __builtin_amdgcn_s_sleep(1);
        }
      }
      __syncthreads();
      // hoisted loads: issue ALL 32 8B LLC reads, then run the MFMA chain
      const ull* hp = (const ull*)(hseq + (size_t)((t - 1) * 64 + bg * 16 + lr) * 512)
                      + lq * 2;
      ull hu[32];
#pragma unroll
      for (int kk = 0; kk < 16; ++kk) {
        hu[2 * kk]     = __hip_atomic_load(hp + kk * 8,
                                           __ATOMIC_RELAXED, __HIP_MEMORY_SCOPE_AGENT);
        hu[2 * kk + 1] = __hip_atomic_load(hp + kk * 8 + 1,
                                           __ATOMIC_RELAXED, __HIP_MEMORY_SCOPE_AGENT);
      }
#pragma unroll
      for (int kk = 0; kk < 16; ++kk) {
        union { ull u[2]; short8 v; } hv;
        hv.u[0] = hu[2 * kk];
        hv.u[1] = hu[2 * kk + 1];
        a0 = mfma_bf16(hv.v, B0[kk], a0);
        a1 = mfma_bf16(hv.v, B1[kk], a1);
      }
    }
#pragma unroll
    for (int r = 0; r < 4; ++r) {
      gbuf[w][lq * 4 + r][lr] = a0[r];
      gbuf[w][lq * 4 + r][16 + lr] = a1[r];
    }
    __syncthreads();
    {
      float gi = gbuf[0][bl][uu] + xi0, gf = gbuf[1][bl][uu] + xf0;
      float gg = gbuf[2][bl][uu] + xg0, go = gbuf[3][bl][uu] + xo0;
      float c = sigm_f(gf) * c0 + sigm_f(gi) * tanh_f(gg);
      c0 = c;
      hbuf[bl][uu] = __float2bfloat16(sigm_f(go) * tanh_f(c));
    }
    {
      float gi = gbuf[0][bl + 8][uu] + xi1, gf = gbuf[1][bl + 8][uu] + xf1;
      float gg = gbuf[2][bl + 8][uu] + xg1, go = gbuf[3][bl + 8][uu] + xo1;
      float c = sigm_f(gf) * c1 + sigm_f(gi) * tanh_f(gg);
      c1 = c;
      hbuf[bl + 8][uu] = __float2bfloat16(sigm_f(go) * tanh_f(c));
    }
    __syncthreads();
    if (tid < 128) {   // 16 rows x 8 ull = our 16x32 h slice
      int r = tid >> 3, g = tid & 7;
      ull val = *(const ull*)(&hbuf[r][g * 4]);
      ull* dst = (ull*)(hseq + (size_t)(t * 64 + bg * 16 + r) * 512 + ug * 32) + g;
      __hip_atomic_store(dst, val, __ATOMIC_RELAXED, __HIP_MEMORY_SCOPE_AGENT);
    }
    __builtin_amdgcn_s_waitcnt(0);   // per-wave: h stores acked at LLC
    __syncthreads();                 // all waves done
    if (tid == 0)
      __hip_atomic_store(cnt + (t * 4 + bg) * 32 + ug, 1u,
                         __ATOMIC_RELAXED, __HIP_MEMORY_SCOPE_AGENT);
  }
}

extern "C" void kernel_launch(void* const* d_in, const int* in_sizes, int n_in,
                              void* d_out, int out_size, void* d_ws, size_t ws_size,
                              hipStream_t stream) {
  const float* feat = (const float*)d_in[0];
  const int* caps   = (const int*)d_in[1];
  const float* emb  = (const float*)d_in[2];
  const float* Wih  = (const float*)d_in[3];
  const float* Whh  = (const float*)d_in[4];
  const float* bih  = (const float*)d_in[5];
  const float* bhh  = (const float*)d_in[6];
  const float* fcW  = (const float*)d_in[7];
  const float* fcb  = (const float*)d_in[8];
  float* out = (float*)d_out;                  // [64,32,10000] fp32

  const size_t MB = 1048576;
  char* ws = (char*)d_ws;
  __hip_bfloat16* Xs   = (__hip_bfloat16*)(ws);             // 2 MB  [2048,512]
  __hip_bfloat16* WhhB = (__hip_bfloat16*)(ws + 2 * MB);    // 2 MB
  __hip_bfloat16* WihB = (__hip_bfloat16*)(ws + 4 * MB);    // 2 MB
  float*          xprj = (float*)(ws + 6 * MB);             // 16 MB [2048,2048]
  __hip_bfloat16* hseq = (__hip_bfloat16*)(ws + 22 * MB);   // 2 MB  [2048,512]
  unsigned*       cnt  = (unsigned*)(ws + 24 * MB);         // 16 KB [32][4] flag rows
  __hip_bfloat16* fcWB = (__hip_bfloat16*)(ws + 24 * MB + 16384);  // 9.77 MB
  const size_t need = 24 * MB + 16384 + (size_t)10000 * 512 * 2;
  const int doFc = (ws_size >= need);

  hipMemsetAsync(cnt, 0, 16384, stream);

  int rows = doFc ? 16144 : 6144;   // Xs 2048 | WhhB 2048 | WihB 2048 | fcWB 10000
  prep<<<rows / 4, 256, 0, stream>>>(feat, caps, emb, Whh, Wih, fcW,
                                     Xs, WhhB, WihB, fcWB);

  gemm_nt<<<dim3(16, 16), 256, 0, stream>>>(Xs, WihB, bih, bhh, xprj,
                                            2048, 2048, 0, 1);

  lstm_seq<<<64, 256, 0, stream>>>(xprj, WhhB, hseq, cnt);

  if (doFc)
    gemm_nt<<<dim3(16, 79), 256, 0, stream>>>(hseq, fcWB, fcb, nullptr, out,
                                              10000, 10000, 1, 1);
  else
    gemm_nt<<<dim3(16, 79), 256, 0, stream>>>(hseq, fcW, fcb, nullptr, out,
                                              10000, 10000, 1, 0);
}

// Round 3
// 341.538 us; speedup vs baseline: 1.1178x; 1.1178x over previous
//
#include <hip/hip_runtime.h>
#include <hip/hip_bf16.h>
#include <stdint.h>

typedef __attribute__((ext_vector_type(8))) short short8;   // 8 bf16 in 4 VGPRs
typedef __attribute__((ext_vector_type(4))) float floatx4;
typedef unsigned long long ull;

__device__ __forceinline__ floatx4 mfma_bf16(short8 a, short8 b, floatx4 c) {
  return __builtin_amdgcn_mfma_f32_16x16x32_bf16(a, b, c, 0, 0, 0);
}

// async global->LDS, 16B per lane; lds must be the wave-uniform base (lane lands at +lane*16)
__device__ __forceinline__ void async16(const void* g, void* lds) {
  __builtin_amdgcn_global_load_lds(
      (const __attribute__((address_space(1))) unsigned int*)g,
      (__attribute__((address_space(3))) unsigned int*)lds, 16, 0, 0);
}

// convert 8 contiguous fp32 -> 8 bf16 (one 16B store)
__device__ __forceinline__ void cvt8_store(const float* __restrict__ src,
                                           __hip_bfloat16* __restrict__ dst) {
  float4 a = *(const float4*)src;
  float4 b = *(const float4*)(src + 4);
  __hip_bfloat16 t[8];
  t[0] = __float2bfloat16(a.x); t[1] = __float2bfloat16(a.y);
  t[2] = __float2bfloat16(a.z); t[3] = __float2bfloat16(a.w);
  t[4] = __float2bfloat16(b.x); t[5] = __float2bfloat16(b.y);
  t[6] = __float2bfloat16(b.z); t[7] = __float2bfloat16(b.w);
  *(uint4*)dst = *(const uint4*)t;
}

// ---------------- prep: r<2048 Xs gather | <4096 WhhB | <6144 WihB | else fcWB
__global__ __launch_bounds__(256) void prep(
    const float* __restrict__ feat, const int* __restrict__ caps,
    const float* __restrict__ emb,  const float* __restrict__ Whh,
    const float* __restrict__ Wih,  const float* __restrict__ fcW,
    __hip_bfloat16* __restrict__ Xs,   __hip_bfloat16* __restrict__ WhhB,
    __hip_bfloat16* __restrict__ WihB, __hip_bfloat16* __restrict__ fcWB) {
  int tid = blockIdx.x * 256 + threadIdx.x;
  int r = tid >> 6;
  int ch = (tid & 63) * 8;
  const float* src;
  __hip_bfloat16* dst;
  if (r < 2048) {
    int t = r >> 6, b = r & 63;
    bool i64 = (caps[1] == 0) & (caps[3] == 0) & (caps[5] == 0) & (caps[7] == 0) &
               (caps[9] == 0) & (caps[11] == 0) & (caps[13] == 0);
    if (t == 0) {
      src = feat + (size_t)b * 512 + ch;
    } else {
      int idx = i64 ? caps[(size_t)(b * 32 + t) * 2] : caps[b * 32 + t];
      idx = idx < 0 ? 0 : (idx > 9999 ? 9999 : idx);
      src = emb + (size_t)idx * 512 + ch;
    }
    dst = Xs + (size_t)r * 512 + ch;
  } else if (r < 4096) {
    src = Whh + (size_t)(r - 2048) * 512 + ch;  dst = WhhB + (size_t)(r - 2048) * 512 + ch;
  } else if (r < 6144) {
    src = Wih + (size_t)(r - 4096) * 512 + ch;  dst = WihB + (size_t)(r - 4096) * 512 + ch;
  } else {
    src = fcW + (size_t)(r - 6144) * 512 + ch;  dst = fcWB + (size_t)(r - 6144) * 512 + ch;
  }
  cvt8_store(src, dst);
}

// ---------------- NT GEMM: C[M x N] = A[M x 512](bf16) * B[N x 512]^T + bias
// mode 0: outF[row*ldc+col] = acc + b1[col] + b2[col]
// mode 1: outF[((row&63)*32+(row>>6))*ldc+col] = acc + b1[col]   (row = t*64+b -> [B,T,V])
__global__ __launch_bounds__(256) void gemm_nt(
    const __hip_bfloat16* __restrict__ A,
    const void* __restrict__ Bv,
    const float* __restrict__ b1,
    const float* __restrict__ b2,
    float* __restrict__ outF,
    int Nrows, int ldc, int mode, int bf16B) {
  const int K = 512;
  __shared__ __align__(16) __hip_bfloat16 As[128 * 32];
  __shared__ __align__(16) __hip_bfloat16 Bs[128 * 32];
  const int tid = threadIdx.x;
  const int ib = blockIdx.x, jb = blockIdx.y;
  const int w = tid >> 6, l = tid & 63, lr = l & 15, lq = l >> 4;
  const int wr = (w & 1) * 64, wc = (w >> 1) * 64;
  floatx4 acc[4][4] = {};
  for (int kt = 0; kt < 16; ++kt) {
    const int k0 = kt * 32;
#pragma unroll
    for (int it = 0; it < 2; ++it) {
      const int flat0 = it * 256 + w * 64;   // wave-uniform LDS base index
      const int flat = flat0 + l;
      const int row = flat >> 2, c8 = (flat & 3) * 8;
      async16(A + (size_t)(ib * 128 + row) * K + k0 + c8, As + flat0 * 8);
      int rb = jb * 128 + row;
      if (rb > Nrows - 1) rb = Nrows - 1;    // clamp tail (dup reads; cols guarded on store)
      if (bf16B) {
        async16((const __hip_bfloat16*)Bv + (size_t)rb * K + k0 + c8, Bs + flat0 * 8);
      } else {
        cvt8_store((const float*)Bv + (size_t)rb * K + k0 + c8, Bs + flat * 8);
      }
    }
    __syncthreads();
    short8 af[4], bfr[4];
#pragma unroll
    for (int mt = 0; mt < 4; ++mt)
      af[mt] = *(const short8*)(As + (wr + mt * 16 + lr) * 32 + lq * 8);
#pragma unroll
    for (int nt = 0; nt < 4; ++nt)
      bfr[nt] = *(const short8*)(Bs + (wc + nt * 16 + lr) * 32 + lq * 8);
#pragma unroll
    for (int mt = 0; mt < 4; ++mt)
#pragma unroll
      for (int nt = 0; nt < 4; ++nt)
        acc[mt][nt] = mfma_bf16(af[mt], bfr[nt], acc[mt][nt]);
    __syncthreads();
  }
#pragma unroll
  for (int mt = 0; mt < 4; ++mt) {
#pragma unroll
    for (int nt = 0; nt < 4; ++nt) {
      int col = jb * 128 + wc + nt * 16 + lr;
      if (col < Nrows) {
        float bias = b1[col] + (b2 ? b2[col] : 0.f);
#pragma unroll
        for (int r = 0; r < 4; ++r) {
          int row = ib * 128 + wr + mt * 16 + lq * 4 + r;
          size_t orow = mode ? (size_t)((row & 63) * 32 + (row >> 6)) : (size_t)row;
          outF[orow * ldc + col] = acc[mt][nt][r] + bias;
        }
      }
    }
  }
}

// ---------------- standalone LSTM (round-0 body, known 182 us) — fallback path
__global__ __launch_bounds__(256, 1) void lstm_seq(
    const float* __restrict__ xp,            // [32][64][2048] fp32 (biases included)
    const __hip_bfloat16* __restrict__ Whh,  // [2048][512] bf16
    __hip_bfloat16* __restrict__ hseq,       // [32][64][512] bf16
    unsigned* __restrict__ cnt) {            // [32][4] counters, 128 B apart
  const int bg = blockIdx.x >> 4;
  const int ug = blockIdx.x & 15;
  const int tid = threadIdx.x;
  const int w = tid >> 6, l = tid & 63, lr = l & 15, lq = l >> 4;
  const int bl = tid >> 5, uu = tid & 31;
  __shared__ float gbuf[4][16][32];
  __shared__ __align__(8) __hip_bfloat16 hbuf[16][32];
  float c0 = 0.f, c1 = 0.f;

  short8 B0[16], B1[16];
  {
    const __hip_bfloat16* w0 = Whh + (size_t)(w * 512 + ug * 32 + lr) * 512 + lq * 8;
    const __hip_bfloat16* w1 = w0 + (size_t)16 * 512;
#pragma unroll
    for (int kk = 0; kk < 16; ++kk) {
      B0[kk] = *(const short8*)(w0 + kk * 32);
      B1[kk] = *(const short8*)(w1 + kk * 32);
    }
  }

  for (int t = 0; t < 32; ++t) {
    const float* xr0 = xp + ((size_t)t * 64 + bg * 16 + bl) * 2048 + ug * 32 + uu;
    const float* xr1 = xr0 + (size_t)8 * 2048;
    float xi0 = xr0[0], xf0 = xr0[512], xg0 = xr0[1024], xo0 = xr0[1536];
    float xi1 = xr1[0], xf1 = xr1[512], xg1 = xr1[1024], xo1 = xr1[1536];

    floatx4 a0 = {}, a1 = {};
    if (t > 0) {
      if (tid == 0) {
        const unsigned* f = cnt + ((t - 1) * 4 + bg) * 32;
        while (__hip_atomic_load(f, __ATOMIC_RELAXED, __HIP_MEMORY_SCOPE_AGENT) < 16u)
          __builtin_amdgcn_s_sleep(1);
      }
      __syncthreads();
      const ull* hp = (const ull*)(hseq + (size_t)((t - 1) * 64 + bg * 16 + lr) * 512);
#pragma unroll
      for (int kk = 0; kk < 16; ++kk) {
        union { ull u[2]; short8 v; } hv;
        hv.u[0] = __hip_atomic_load(hp + kk * 8 + lq * 2,
                                    __ATOMIC_RELAXED, __HIP_MEMORY_SCOPE_AGENT);
        hv.u[1] = __hip_atomic_load(hp + kk * 8 + lq * 2 + 1,
                                    __ATOMIC_RELAXED, __HIP_MEMORY_SCOPE_AGENT);
        a0 = mfma_bf16(hv.v, B0[kk], a0);
        a1 = mfma_bf16(hv.v, B1[kk], a1);
      }
    }
#pragma unroll
    for (int r = 0; r < 4; ++r) {
      gbuf[w][lq * 4 + r][lr] = a0[r];
      gbuf[w][lq * 4 + r][16 + lr] = a1[r];
    }
    __syncthreads();
    {
      float gi = gbuf[0][bl][uu] + xi0, gf = gbuf[1][bl][uu] + xf0;
      float gg = gbuf[2][bl][uu] + xg0, go = gbuf[3][bl][uu] + xo0;
      float c = 1.f / (1.f + __expf(-gf)) * c0 + 1.f / (1.f + __expf(-gi)) * tanhf(gg);
      c0 = c;
      hbuf[bl][uu] = __float2bfloat16(1.f / (1.f + __expf(-go)) * tanhf(c));
    }
    {
      float gi = gbuf[0][bl + 8][uu] + xi1, gf = gbuf[1][bl + 8][uu] + xf1;
      float gg = gbuf[2][bl + 8][uu] + xg1, go = gbuf[3][bl + 8][uu] + xo1;
      float c = 1.f / (1.f + __expf(-gf)) * c1 + 1.f / (1.f + __expf(-gi)) * tanhf(gg);
      c1 = c;
      hbuf[bl + 8][uu] = __float2bfloat16(1.f / (1.f + __expf(-go)) * tanhf(c));
    }
    __syncthreads();
    if (tid < 128) {
      int r = tid >> 3, g = tid & 7;
      ull val = *(const ull*)(&hbuf[r][g * 4]);
      ull* dst = (ull*)(hseq + (size_t)(t * 64 + bg * 16 + r) * 512 + ug * 32) + g;
      __hip_atomic_store(dst, val, __ATOMIC_RELAXED, __HIP_MEMORY_SCOPE_AGENT);
    }
    __builtin_amdgcn_s_waitcnt(0);
    __syncthreads();
    if (tid == 0)
      __hip_atomic_fetch_add(cnt + (t * 4 + bg) * 32, 1u,
                             __ATOMIC_RELAXED, __HIP_MEMORY_SCOPE_AGENT);
  }
}

// ---------------- fused LSTM + FC, v2 (contention-isolated):
//  blocks 0..63  : LSTM chain, byte-identical mechanics to lstm_seq (round-0).
//  block  64     : AGGREGATOR — the ONLY poller of the per-(t,bg) counter lines;
//                  republishes a monotone frontier `tfront` to a cold line.
//  blocks 65..255: FC workers — poll the single tfront word (never the counter
//                  lines), then compute a 128x128 tile. All blocks join the tile
//                  queue when their primary role completes.
//  grid = 256 = CU count -> all blocks co-resident, no dispatch-order hazard.
__global__ __launch_bounds__(256, 1) void lstm_fc(
    const float* __restrict__ xp,
    const __hip_bfloat16* __restrict__ Whh,
    __hip_bfloat16* __restrict__ hseq,
    unsigned* __restrict__ cnt,
    const __hip_bfloat16* __restrict__ fcWB,
    const float* __restrict__ fcb,
    float* __restrict__ out) {
  __shared__ __align__(16) char sm[16 * 1024 + 16];
  const int tid = threadIdx.x;
  const int w = tid >> 6, l = tid & 63, lr = l & 15, lq = l >> 4;
  // tfront/queue live in unused words of the t=0 flag rows (cold after step 0)
  unsigned* tfront = cnt + 16;        // word 16 of row (t=0,bg=0)
  unsigned* queue  = cnt + 48;        // word 16 of row (t=0,bg=1)

  if (blockIdx.x < 64) {
    // ---------------- LSTM phase (round-0 mechanics, unchanged) ----------------
    const int bg = blockIdx.x >> 4;
    const int ug = blockIdx.x & 15;
    const int bl = tid >> 5, uu = tid & 31;
    float (*gbuf)[16][32] = (float (*)[16][32])sm;                    // 8 KB
    __hip_bfloat16 (*hbuf)[32] = (__hip_bfloat16 (*)[32])(sm + 8192); // 1 KB
    float c0 = 0.f, c1 = 0.f;

    short8 B0[16], B1[16];
    {
      const __hip_bfloat16* w0 = Whh + (size_t)(w * 512 + ug * 32 + lr) * 512 + lq * 8;
      const __hip_bfloat16* w1 = w0 + (size_t)16 * 512;
#pragma unroll
      for (int kk = 0; kk < 16; ++kk) {
        B0[kk] = *(const short8*)(w0 + kk * 32);
        B1[kk] = *(const short8*)(w1 + kk * 32);
      }
    }

    for (int t = 0; t < 32; ++t) {
      const float* xr0 = xp + ((size_t)t * 64 + bg * 16 + bl) * 2048 + ug * 32 + uu;
      const float* xr1 = xr0 + (size_t)8 * 2048;
      float xi0 = xr0[0], xf0 = xr0[512], xg0 = xr0[1024], xo0 = xr0[1536];
      float xi1 = xr1[0], xf1 = xr1[512], xg1 = xr1[1024], xo1 = xr1[1536];

      floatx4 a0 = {}, a1 = {};
      if (t > 0) {
        if (tid == 0) {
          const unsigned* f = cnt + ((t - 1) * 4 + bg) * 32;
          while (__hip_atomic_load(f, __ATOMIC_RELAXED, __HIP_MEMORY_SCOPE_AGENT) < 16u)
            __builtin_amdgcn_s_sleep(1);
        }
        __syncthreads();
        const ull* hp = (const ull*)(hseq + (size_t)((t - 1) * 64 + bg * 16 + lr) * 512);
#pragma unroll
        for (int kk = 0; kk < 16; ++kk) {
          union { ull u[2]; short8 v; } hv;
          hv.u[0] = __hip_atomic_load(hp + kk * 8 + lq * 2,
                                      __ATOMIC_RELAXED, __HIP_MEMORY_SCOPE_AGENT);
          hv.u[1] = __hip_atomic_load(hp + kk * 8 + lq * 2 + 1,
                                      __ATOMIC_RELAXED, __HIP_MEMORY_SCOPE_AGENT);
          a0 = mfma_bf16(hv.v, B0[kk], a0);
          a1 = mfma_bf16(hv.v, B1[kk], a1);
        }
      }
#pragma unroll
      for (int r = 0; r < 4; ++r) {
        gbuf[w][lq * 4 + r][lr] = a0[r];
        gbuf[w][lq * 4 + r][16 + lr] = a1[r];
      }
      __syncthreads();
      {
        float gi = gbuf[0][bl][uu] + xi0, gf = gbuf[1][bl][uu] + xf0;
        float gg = gbuf[2][bl][uu] + xg0, go = gbuf[3][bl][uu] + xo0;
        float c = 1.f / (1.f + __expf(-gf)) * c0 + 1.f / (1.f + __expf(-gi)) * tanhf(gg);
        c0 = c;
        hbuf[bl][uu] = __float2bfloat16(1.f / (1.f + __expf(-go)) * tanhf(c));
      }
      {
        float gi = gbuf[0][bl + 8][uu] + xi1, gf = gbuf[1][bl + 8][uu] + xf1;
        float gg = gbuf[2][bl + 8][uu] + xg1, go = gbuf[3][bl + 8][uu] + xo1;
        float c = 1.f / (1.f + __expf(-gf)) * c1 + 1.f / (1.f + __expf(-gi)) * tanhf(gg);
        c1 = c;
        hbuf[bl + 8][uu] = __float2bfloat16(1.f / (1.f + __expf(-go)) * tanhf(c));
      }
      __syncthreads();
      if (tid < 128) {
        int r = tid >> 3, g = tid & 7;
        ull val = *(const ull*)(&hbuf[r][g * 4]);
        ull* dst = (ull*)(hseq + (size_t)(t * 64 + bg * 16 + r) * 512 + ug * 32) + g;
        __hip_atomic_store(dst, val, __ATOMIC_RELAXED, __HIP_MEMORY_SCOPE_AGENT);
      }
      __builtin_amdgcn_s_waitcnt(0);
      __syncthreads();
      if (tid == 0)
        __hip_atomic_fetch_add(cnt + (t * 4 + bg) * 32, 1u,
                               __ATOMIC_RELAXED, __HIP_MEMORY_SCOPE_AGENT);
    }
  } else if (blockIdx.x == 64) {
    // ---------------- aggregator: sole poller of the counter lines ----------------
    if (tid == 0) {
      for (int t = 0; t < 32; ++t) {
        for (int bg = 0; bg < 4; ++bg) {
          const unsigned* f = cnt + (t * 4 + bg) * 32;
          while (__hip_atomic_load(f, __ATOMIC_RELAXED, __HIP_MEMORY_SCOPE_AGENT) < 16u)
            __builtin_amdgcn_s_sleep(8);
        }
        __hip_atomic_store(tfront, (unsigned)(t + 1),
                           __ATOMIC_RELAXED, __HIP_MEMORY_SCOPE_AGENT);
      }
    }
    // other threads fall through and park at the worker loop's first barrier
  }

  // ---------------- FC worker pool (all 256 blocks end up here) ----------------
  __hip_bfloat16* As = (__hip_bfloat16*)sm;           // 8 KB
  __hip_bfloat16* Bs = As + 128 * 32;                 // 8 KB
  int* nslot = (int*)(sm + 16384);
  const int wr = (w & 1) * 64, wc = (w >> 1) * 64;

  for (;;) {
    __syncthreads();   // LDS handoff (role->worker and between tiles)
    if (tid == 0)
      *nslot = (int)__hip_atomic_fetch_add(queue, 1u,
                                           __ATOMIC_RELAXED, __HIP_MEMORY_SCOPE_AGENT);
    __syncthreads();
    const int n = *nslot;
    if (n >= 16 * 79) break;
    const int ib = n / 79, jb = n - ib * 79;   // ib ascending == t ascending

    if (tid == 0) {
      // tile needs hseq rows of t = 2*ib and 2*ib+1  ->  frontier >= 2*ib+2.
      const unsigned need = (unsigned)(2 * ib + 2);
      while (__hip_atomic_load(tfront, __ATOMIC_RELAXED, __HIP_MEMORY_SCOPE_AGENT) < need)
        __builtin_amdgcn_s_sleep(16);
    }
    __syncthreads();

    floatx4 acc[4][4] = {};
    for (int kt = 0; kt < 16; ++kt) {
      const int k0 = kt * 32;
#pragma unroll
      for (int it = 0; it < 2; ++it) {
        const int flat0 = it * 256 + w * 64;
        const int flat = flat0 + l;
        const int row = flat >> 2, c8 = (flat & 3) * 8;
        // A from hseq: LLC atomic loads (same-kernel producer), then ds_write
        const ull* ap = (const ull*)(hseq + (size_t)(ib * 128 + row) * 512 + k0 + c8);
        union { ull u[2]; uint4 q; } av;
        av.u[0] = __hip_atomic_load(ap,     __ATOMIC_RELAXED, __HIP_MEMORY_SCOPE_AGENT);
        av.u[1] = __hip_atomic_load(ap + 1, __ATOMIC_RELAXED, __HIP_MEMORY_SCOPE_AGENT);
        *(uint4*)(As + (size_t)flat * 8) = av.q;
        int rb = jb * 128 + row;
        if (rb > 9999) rb = 9999;              // clamp tail; cols guarded on store
        async16(fcWB + (size_t)rb * 512 + k0 + c8, Bs + flat0 * 8);
      }
      __syncthreads();
      short8 af[4], bfr[4];
#pragma unroll
      for (int mt = 0; mt < 4; ++mt)
        af[mt] = *(const short8*)(As + (wr + mt * 16 + lr) * 32 + lq * 8);
#pragma unroll
      for (int nt = 0; nt < 4; ++nt)
        bfr[nt] = *(const short8*)(Bs + (wc + nt * 16 + lr) * 32 + lq * 8);
#pragma unroll
      for (int mt = 0; mt < 4; ++mt)
#pragma unroll
        for (int nt = 0; nt < 4; ++nt)
          acc[mt][nt] = mfma_bf16(af[mt], bfr[nt], acc[mt][nt]);
      __syncthreads();
    }
#pragma unroll
    for (int mt = 0; mt < 4; ++mt) {
#pragma unroll
      for (int nt = 0; nt < 4; ++nt) {
        int col = jb * 128 + wc + nt * 16 + lr;
        if (col < 10000) {
          float bias = fcb[col];
#pragma unroll
          for (int r = 0; r < 4; ++r) {
            int row = ib * 128 + wr + mt * 16 + lq * 4 + r;
            size_t orow = (size_t)((row & 63) * 32 + (row >> 6));   // [B,T,V]
            out[orow * 10000 + col] = acc[mt][nt][r] + bias;
          }
        }
      }
    }
  }
}

extern "C" void kernel_launch(void* const* d_in, const int* in_sizes, int n_in,
                              void* d_out, int out_size, void* d_ws, size_t ws_size,
                              hipStream_t stream) {
  const float* feat = (const float*)d_in[0];
  const int* caps   = (const int*)d_in[1];
  const float* emb  = (const float*)d_in[2];
  const float* Wih  = (const float*)d_in[3];
  const float* Whh  = (const float*)d_in[4];
  const float* bih  = (const float*)d_in[5];
  const float* bhh  = (const float*)d_in[6];
  const float* fcW  = (const float*)d_in[7];
  const float* fcb  = (const float*)d_in[8];
  float* out = (float*)d_out;                  // [64,32,10000] fp32

  const size_t MB = 1048576;
  char* ws = (char*)d_ws;
  __hip_bfloat16* Xs   = (__hip_bfloat16*)(ws);             // 2 MB  [2048,512]
  __hip_bfloat16* WhhB = (__hip_bfloat16*)(ws + 2 * MB);    // 2 MB
  __hip_bfloat16* WihB = (__hip_bfloat16*)(ws + 4 * MB);    // 2 MB
  float*          xprj = (float*)(ws + 6 * MB);             // 16 MB [2048,2048]
  __hip_bfloat16* hseq = (__hip_bfloat16*)(ws + 22 * MB);   // 2 MB  [2048,512]
  unsigned*       cnt  = (unsigned*)(ws + 24 * MB);         // 16 KB flag rows + tfront/queue
  __hip_bfloat16* fcWB = (__hip_bfloat16*)(ws + 24 * MB + 16384);  // 9.77 MB
  const size_t need = 24 * MB + 16384 + (size_t)10000 * 512 * 2;
  const int doFc = (ws_size >= need);

  hipMemsetAsync(cnt, 0, 16384, stream);

  int rows = doFc ? 16144 : 6144;   // Xs 2048 | WhhB 2048 | WihB 2048 | fcWB 10000
  prep<<<rows / 4, 256, 0, stream>>>(feat, caps, emb, Whh, Wih, fcW,
                                     Xs, WhhB, WihB, fcWB);

  gemm_nt<<<dim3(16, 16), 256, 0, stream>>>(Xs, WihB, bih, bhh, xprj,
                                            2048, 2048, 0, 1);

  if (doFc) {
    // fused LSTM + output-projection, aggregator-isolated polling
    lstm_fc<<<256, 256, 0, stream>>>(xprj, WhhB, hseq, cnt, fcWB, fcb, out);
  } else {
    lstm_seq<<<64, 256, 0, stream>>>(xprj, WhhB, hseq, cnt);
    gemm_nt<<<dim3(16, 79), 256, 0, stream>>>(hseq, fcW, fcb, nullptr, out,
                                              10000, 10000, 1, 0);
  }
}

// Round 4
// 341.383 us; speedup vs baseline: 1.1183x; 1.0005x over previous
//
#include <hip/hip_runtime.h>
#include <hip/hip_bf16.h>
#include <stdint.h>

typedef __attribute__((ext_vector_type(8))) short short8;   // 8 bf16 in 4 VGPRs
typedef __attribute__((ext_vector_type(4))) float floatx4;
typedef unsigned long long ull;

#define AT_LD(p)    __hip_atomic_load((p), __ATOMIC_RELAXED, __HIP_MEMORY_SCOPE_AGENT)
#define AT_ST(p, v) __hip_atomic_store((p), (v), __ATOMIC_RELAXED, __HIP_MEMORY_SCOPE_AGENT)
#define AT_ADD(p, v) __hip_atomic_fetch_add((p), (v), __ATOMIC_RELAXED, __HIP_MEMORY_SCOPE_AGENT)

__device__ __forceinline__ floatx4 mfma_bf16(short8 a, short8 b, floatx4 c) {
  return __builtin_amdgcn_mfma_f32_16x16x32_bf16(a, b, c, 0, 0, 0);
}

// convert 8 contiguous fp32 -> 8 bf16 (one 16B store to LDS/global)
__device__ __forceinline__ void cvt8_store(const float* __restrict__ src,
                                           __hip_bfloat16* __restrict__ dst) {
  float4 a = *(const float4*)src;
  float4 b = *(const float4*)(src + 4);
  __hip_bfloat16 t[8];
  t[0] = __float2bfloat16(a.x); t[1] = __float2bfloat16(a.y);
  t[2] = __float2bfloat16(a.z); t[3] = __float2bfloat16(a.w);
  t[4] = __float2bfloat16(b.x); t[5] = __float2bfloat16(b.y);
  t[6] = __float2bfloat16(b.z); t[7] = __float2bfloat16(b.w);
  *(uint4*)dst = *(const uint4*)t;
}

// convert 8 contiguous fp32 -> short8 bf16 fragment in registers
__device__ __forceinline__ short8 cvt8_frag(const float* __restrict__ src) {
  float4 a = *(const float4*)src;
  float4 b = *(const float4*)(src + 4);
  union { __hip_bfloat16 h[8]; short8 s; } u;
  u.h[0] = __float2bfloat16(a.x); u.h[1] = __float2bfloat16(a.y);
  u.h[2] = __float2bfloat16(a.z); u.h[3] = __float2bfloat16(a.w);
  u.h[4] = __float2bfloat16(b.x); u.h[5] = __float2bfloat16(b.y);
  u.h[6] = __float2bfloat16(b.z); u.h[7] = __float2bfloat16(b.w);
  return u.s;
}

// =====================================================================
// ONE mega-kernel, grid = 256 blocks = CU count (all co-resident).
//  blocks 0..63  : LSTM chain. Prologue converts own Whh slice fp32->bf16
//                  into regs. Step t gated on xfront (xprj readiness).
//  block  64     : aggregator — sole poller of xcnt then of the per-(t,bg)
//                  h-flags; republishes xfront / tfront on cold lines.
//  blocks 65..255: workers. Queue entries 0..255 = xprj tiles (gather+cvt
//                  A from feat/emb, cvt B from Wih, atomic-store C) in
//                  ib-ascending (= t-ascending) order; entries 256..1519 =
//                  fc tiles (atomic A from hseq, cvt B from fcW, normal C
//                  stores to out), gated by tfront. lstm blocks + aggregator
//                  join the pool when their role completes.
// Cross-block dataflow inside the kernel uses relaxed agent-scope atomics
// (LLC write-through / LLC read) + s_waitcnt(0) before flag bumps —
// the pattern proven by rounds 0..3.
// =====================================================================
__global__ __launch_bounds__(256, 1) void fused_all(
    const float* __restrict__ feat,   // [64][512]
    const int*   __restrict__ caps,   // [64][32] int32 or int64
    const float* __restrict__ emb,    // [10000][512]
    const float* __restrict__ Wih,    // [2048][512]
    const float* __restrict__ Whh,    // [2048][512]
    const float* __restrict__ bih,    // [2048]
    const float* __restrict__ bhh,    // [2048]
    const float* __restrict__ fcW,    // [10000][512]
    const float* __restrict__ fcb,    // [10000]
    float* __restrict__ xprj,         // ws: [2048][2048] fp32
    __hip_bfloat16* __restrict__ hseq,// ws: [2048][512] bf16
    unsigned* __restrict__ cnt,       // ws: 32 KB zeroed (flags + aux)
    float* __restrict__ out) {        // [64][32][10000] fp32
  __shared__ __align__(16) char sm[16 * 1024 + 16];
  const int tid = threadIdx.x;
  const int w = tid >> 6, l = tid & 63, lr = l & 15, lq = l >> 4;

  unsigned* aux    = cnt + 4096;          // second 16 KB: cold control lines
  unsigned* xcnt   = aux;                 // 16 counters, 128 B apart
  unsigned* xfront = aux + 16 * 32;
  unsigned* tfront = aux + 17 * 32;
  unsigned* queue  = aux + 18 * 32;

  // int64-captions heuristic (tokens <10000 -> high words zero); uniform.
  const bool i64 = (caps[1] == 0) & (caps[3] == 0) & (caps[5] == 0) &
                   (caps[7] == 0) & (caps[9] == 0) & (caps[11] == 0) &
                   (caps[13] == 0);

  if (blockIdx.x < 64) {
    // ---------------- LSTM role (round-0 mechanics + xfront gate) ----------------
    const int bg = blockIdx.x >> 4;   // 0..3  (16 batch rows)
    const int ug = blockIdx.x & 15;   // 0..15 (32 hidden units)
    const int bl = tid >> 5, uu = tid & 31;
    float (*gbuf)[16][32] = (float (*)[16][32])sm;                    // 8 KB
    __hip_bfloat16 (*hbuf)[32] = (__hip_bfloat16 (*)[32])(sm + 8192); // 1 KB
    unsigned* xsh = (unsigned*)(sm + 16384);
    float c0 = 0.f, c1 = 0.f;

    // Whh slice fp32 -> bf16 fragments in regs (replaces prep's WhhB)
    short8 B0[16], B1[16];
    {
      const float* w0 = Whh + (size_t)(w * 512 + ug * 32 + lr) * 512 + lq * 8;
      const float* w1 = w0 + (size_t)16 * 512;
#pragma unroll
      for (int kk = 0; kk < 16; ++kk) {
        B0[kk] = cvt8_frag(w0 + kk * 32);
        B1[kk] = cvt8_frag(w1 + kk * 32);
      }
    }

    unsigned xseen = 0;   // xprj t-pairs known ready (uniform)
    for (int t = 0; t < 32; ++t) {
      // gate on xprj readiness (only active for the first few steps)
      if (xseen * 2 <= (unsigned)t) {
        if (tid == 0) {
          unsigned v;
          while ((v = AT_LD(xfront)) <= (unsigned)(t >> 1))
            __builtin_amdgcn_s_sleep(2);
          *xsh = v;
        }
        __syncthreads();
        xseen = *xsh;
        __syncthreads();
      }
      // prefetch this step's xp (independent of h) — in flight during the spin.
      // atomic agent loads: xprj produced by worker blocks in this kernel.
      const float* xr0 = xprj + ((size_t)t * 64 + bg * 16 + bl) * 2048 + ug * 32 + uu;
      const float* xr1 = xr0 + (size_t)8 * 2048;
      float xi0 = AT_LD(xr0),        xf0 = AT_LD(xr0 + 512);
      float xg0 = AT_LD(xr0 + 1024), xo0 = AT_LD(xr0 + 1536);
      float xi1 = AT_LD(xr1),        xf1 = AT_LD(xr1 + 512);
      float xg1 = AT_LD(xr1 + 1024), xo1 = AT_LD(xr1 + 1536);

      floatx4 a0 = {}, a1 = {};
      if (t > 0) {
        if (tid == 0) {
          const unsigned* f = cnt + ((t - 1) * 4 + bg) * 32;
          while (AT_LD(f) < 16u) __builtin_amdgcn_s_sleep(1);
        }
        __syncthreads();
        const ull* hp = (const ull*)(hseq + (size_t)((t - 1) * 64 + bg * 16 + lr) * 512);
#pragma unroll
        for (int kk = 0; kk < 16; ++kk) {
          union { ull u[2]; short8 v; } hv;
          hv.u[0] = AT_LD(hp + kk * 8 + lq * 2);
          hv.u[1] = AT_LD(hp + kk * 8 + lq * 2 + 1);
          a0 = mfma_bf16(hv.v, B0[kk], a0);
          a1 = mfma_bf16(hv.v, B1[kk], a1);
        }
      }
#pragma unroll
      for (int r = 0; r < 4; ++r) {
        gbuf[w][lq * 4 + r][lr] = a0[r];
        gbuf[w][lq * 4 + r][16 + lr] = a1[r];
      }
      __syncthreads();
      {
        float gi = gbuf[0][bl][uu] + xi0, gf = gbuf[1][bl][uu] + xf0;
        float gg = gbuf[2][bl][uu] + xg0, go = gbuf[3][bl][uu] + xo0;
        float c = 1.f / (1.f + __expf(-gf)) * c0 + 1.f / (1.f + __expf(-gi)) * tanhf(gg);
        c0 = c;
        hbuf[bl][uu] = __float2bfloat16(1.f / (1.f + __expf(-go)) * tanhf(c));
      }
      {
        float gi = gbuf[0][bl + 8][uu] + xi1, gf = gbuf[1][bl + 8][uu] + xf1;
        float gg = gbuf[2][bl + 8][uu] + xg1, go = gbuf[3][bl + 8][uu] + xo1;
        float c = 1.f / (1.f + __expf(-gf)) * c1 + 1.f / (1.f + __expf(-gi)) * tanhf(gg);
        c1 = c;
        hbuf[bl + 8][uu] = __float2bfloat16(1.f / (1.f + __expf(-go)) * tanhf(c));
      }
      __syncthreads();
      if (tid < 128) {   // 16 rows x 8 ull = our 16x32 h slice
        int r = tid >> 3, g = tid & 7;
        ull val = *(const ull*)(&hbuf[r][g * 4]);
        ull* dst = (ull*)(hseq + (size_t)(t * 64 + bg * 16 + r) * 512 + ug * 32) + g;
        AT_ST(dst, val);
      }
      __builtin_amdgcn_s_waitcnt(0);   // h stores acked at LLC
      __syncthreads();
      if (tid == 0) AT_ADD(cnt + (t * 4 + bg) * 32, 1u);
    }
  } else if (blockIdx.x == 64) {
    // ---------------- aggregator: sole poller of hot counter lines ----------------
    if (tid == 0) {
      for (int ib = 0; ib < 16; ++ib) {
        while (AT_LD(xcnt + ib * 32) < 16u) __builtin_amdgcn_s_sleep(2);
        AT_ST(xfront, (unsigned)(ib + 1));
      }
      for (int t = 0; t < 32; ++t) {
        for (int bg = 0; bg < 4; ++bg) {
          const unsigned* f = cnt + (t * 4 + bg) * 32;
          while (AT_LD(f) < 16u) __builtin_amdgcn_s_sleep(8);
        }
        AT_ST(tfront, (unsigned)(t + 1));
      }
    }
    // other threads fall through and park at the pool's first barrier
  }

  // ---------------- worker pool (all 256 blocks end up here) ----------------
  __hip_bfloat16* As = (__hip_bfloat16*)sm;           // 8 KB
  __hip_bfloat16* Bs = As + 128 * 32;                 // 8 KB
  int* nslot = (int*)(sm + 16384);
  const int wr = (w & 1) * 64, wc = (w >> 1) * 64;
  // per-it staging geometry (fixed per thread)
  const int flatA0 = 0 * 256 + w * 64 + l, flatA1 = 1 * 256 + w * 64 + l;
  const int row0 = flatA0 >> 2, c80 = (flatA0 & 3) * 8;
  const int row1 = flatA1 >> 2, c81 = (flatA1 & 3) * 8;

  for (;;) {
    __syncthreads();   // LDS handoff (role->pool and between tiles)
    if (tid == 0) *nslot = (int)AT_ADD(queue, 1u);
    __syncthreads();
    const int n = *nslot;
    if (n >= 256 + 16 * 79) break;

    if (n < 256) {
      // ============ xprj tile: xprj[ib*128.., jb*128..] = Xs * Wih^T + b ============
      const int ib = n >> 4, jb = n & 15;   // ib ascending == t ascending
      // A source pointers: row r_g = ib*128+row -> t=r_g>>6, b=r_g&63
      const float* sA[2];
      const float* sB[2];
      {
        const int rg0 = ib * 128 + row0, tt0 = rg0 >> 6, b0 = rg0 & 63;
        const int rg1 = ib * 128 + row1, tt1 = rg1 >> 6, b1v = rg1 & 63;
        if (tt0 == 0) sA[0] = feat + (size_t)b0 * 512 + c80;
        else {
          int idx = i64 ? caps[(size_t)(b0 * 32 + tt0) * 2] : caps[b0 * 32 + tt0];
          idx = idx < 0 ? 0 : (idx > 9999 ? 9999 : idx);
          sA[0] = emb + (size_t)idx * 512 + c80;
        }
        if (tt1 == 0) sA[1] = feat + (size_t)b1v * 512 + c81;
        else {
          int idx = i64 ? caps[(size_t)(b1v * 32 + tt1) * 2] : caps[b1v * 32 + tt1];
          idx = idx < 0 ? 0 : (idx > 9999 ? 9999 : idx);
          sA[1] = emb + (size_t)idx * 512 + c81;
        }
        sB[0] = Wih + (size_t)(jb * 128 + row0) * 512 + c80;
        sB[1] = Wih + (size_t)(jb * 128 + row1) * 512 + c81;
      }
      floatx4 acc[4][4] = {};
      for (int kt = 0; kt < 16; ++kt) {
        const int k0 = kt * 32;
        cvt8_store(sA[0] + k0, As + (size_t)flatA0 * 8);
        cvt8_store(sB[0] + k0, Bs + (size_t)flatA0 * 8);
        cvt8_store(sA[1] + k0, As + (size_t)flatA1 * 8);
        cvt8_store(sB[1] + k0, Bs + (size_t)flatA1 * 8);
        __syncthreads();
        short8 af[4], bfr[4];
#pragma unroll
        for (int mt = 0; mt < 4; ++mt)
          af[mt] = *(const short8*)(As + (wr + mt * 16 + lr) * 32 + lq * 8);
#pragma unroll
        for (int nt = 0; nt < 4; ++nt)
          bfr[nt] = *(const short8*)(Bs + (wc + nt * 16 + lr) * 32 + lq * 8);
#pragma unroll
        for (int mt = 0; mt < 4; ++mt)
#pragma unroll
          for (int nt = 0; nt < 4; ++nt)
            acc[mt][nt] = mfma_bf16(af[mt], bfr[nt], acc[mt][nt]);
        __syncthreads();
      }
      // epilogue: agent-scope atomic stores (consumed by lstm blocks this kernel)
#pragma unroll
      for (int mt = 0; mt < 4; ++mt) {
#pragma unroll
        for (int nt = 0; nt < 4; ++nt) {
          int col = jb * 128 + wc + nt * 16 + lr;
          float bias = bih[col] + bhh[col];
#pragma unroll
          for (int r = 0; r < 4; ++r) {
            int row = ib * 128 + wr + mt * 16 + lq * 4 + r;
            AT_ST(xprj + (size_t)row * 2048 + col, acc[mt][nt][r] + bias);
          }
        }
      }
      __builtin_amdgcn_s_waitcnt(0);   // stores acked at LLC
      __syncthreads();
      if (tid == 0) AT_ADD(xcnt + ib * 32, 1u);
    } else {
      // ============ fc tile: out = hseq * fcW^T + fcb ============
      const int m = n - 256;
      const int ib = m / 79, jb = m - ib * 79;   // ib ascending == t ascending
      if (tid == 0) {
        const unsigned need = (unsigned)(2 * ib + 2);
        while (AT_LD(tfront) < need) __builtin_amdgcn_s_sleep(16);
      }
      __syncthreads();
      // B source (fp32 fcW, cvt staging); A from hseq via LLC atomic loads
      int rb0 = jb * 128 + row0; if (rb0 > 9999) rb0 = 9999;
      int rb1 = jb * 128 + row1; if (rb1 > 9999) rb1 = 9999;
      const float* sB0 = fcW + (size_t)rb0 * 512 + c80;
      const float* sB1 = fcW + (size_t)rb1 * 512 + c81;
      const ull* sA0 = (const ull*)(hseq + (size_t)(ib * 128 + row0) * 512 + c80);
      const ull* sA1 = (const ull*)(hseq + (size_t)(ib * 128 + row1) * 512 + c81);
      floatx4 acc[4][4] = {};
      for (int kt = 0; kt < 16; ++kt) {
        const int k0 = kt * 32;
        union { ull u[2]; uint4 q; } av;
        av.u[0] = AT_LD(sA0 + (k0 >> 2));
        av.u[1] = AT_LD(sA0 + (k0 >> 2) + 1);
        *(uint4*)(As + (size_t)flatA0 * 8) = av.q;
        cvt8_store(sB0 + k0, Bs + (size_t)flatA0 * 8);
        av.u[0] = AT_LD(sA1 + (k0 >> 2));
        av.u[1] = AT_LD(sA1 + (k0 >> 2) + 1);
        *(uint4*)(As + (size_t)flatA1 * 8) = av.q;
        cvt8_store(sB1 + k0, Bs + (size_t)flatA1 * 8);
        __syncthreads();
        short8 af[4], bfr[4];
#pragma unroll
        for (int mt = 0; mt < 4; ++mt)
          af[mt] = *(const short8*)(As + (wr + mt * 16 + lr) * 32 + lq * 8);
#pragma unroll
        for (int nt = 0; nt < 4; ++nt)
          bfr[nt] = *(const short8*)(Bs + (wc + nt * 16 + lr) * 32 + lq * 8);
#pragma unroll
        for (int mt = 0; mt < 4; ++mt)
#pragma unroll
          for (int nt = 0; nt < 4; ++nt)
            acc[mt][nt] = mfma_bf16(af[mt], bfr[nt], acc[mt][nt]);
        __syncthreads();
      }
#pragma unroll
      for (int mt = 0; mt < 4; ++mt) {
#pragma unroll
        for (int nt = 0; nt < 4; ++nt) {
          int col = jb * 128 + wc + nt * 16 + lr;
          if (col < 10000) {
            float bias = fcb[col];
#pragma unroll
            for (int r = 0; r < 4; ++r) {
              int row = ib * 128 + wr + mt * 16 + lq * 4 + r;
              size_t orow = (size_t)((row & 63) * 32 + (row >> 6));   // [B,T,V]
              out[orow * 10000 + col] = acc[mt][nt][r] + bias;
            }
          }
        }
      }
    }
  }
}

extern "C" void kernel_launch(void* const* d_in, const int* in_sizes, int n_in,
                              void* d_out, int out_size, void* d_ws, size_t ws_size,
                              hipStream_t stream) {
  const float* feat = (const float*)d_in[0];
  const int* caps   = (const int*)d_in[1];
  const float* emb  = (const float*)d_in[2];
  const float* Wih  = (const float*)d_in[3];
  const float* Whh  = (const float*)d_in[4];
  const float* bih  = (const float*)d_in[5];
  const float* bhh  = (const float*)d_in[6];
  const float* fcW  = (const float*)d_in[7];
  const float* fcb  = (const float*)d_in[8];
  float* out = (float*)d_out;                  // [64,32,10000] fp32

  const size_t MB = 1048576;
  char* ws = (char*)d_ws;
  float*          xprj = (float*)(ws);                      // 16 MB [2048,2048]
  __hip_bfloat16* hseq = (__hip_bfloat16*)(ws + 16 * MB);   // 2 MB  [2048,512]
  unsigned*       cnt  = (unsigned*)(ws + 18 * MB);         // 32 KB flags + aux

  hipMemsetAsync(cnt, 0, 32768, stream);

  fused_all<<<256, 256, 0, stream>>>(feat, caps, emb, Wih, Whh, bih, bhh,
                                     fcW, fcb, xprj, hseq, cnt, out);
}